// Round 12
// baseline (322.858 us; speedup 1.0000x reference)
//
#include <hip/hip_runtime.h>
#include <hip/hip_bf16.h>

typedef __attribute__((ext_vector_type(8))) short short8;
typedef __attribute__((ext_vector_type(4))) float f32x4;
typedef __attribute__((ext_vector_type(4))) unsigned short us4;
typedef __attribute__((ext_vector_type(2))) unsigned uint2v;

union U8 { unsigned u[4]; short8 s; };

__device__ __forceinline__ unsigned short f2b(float f) {
  unsigned u = __float_as_uint(f);
  u += 0x7FFFu + ((u >> 16) & 1u);
  return (unsigned short)(u >> 16);
}
__device__ __forceinline__ unsigned pkbf(float lo, float hi) {
  __hip_bfloat162 h = __float22bfloat162_rn(make_float2(lo, hi));
  unsigned u; __builtin_memcpy(&u, &h, 4);
  return u;
}
// exchange lane bit5 with the (a,b) register-pair bit  (a=vdst, b=vsrc)
__device__ __forceinline__ void swp32(unsigned &a, unsigned &b) {
  uint2v r = __builtin_amdgcn_permlane32_swap(a, b, false, false);
  a = r.x; b = r.y;
}
// exchange lane bit4 with the (a,b) register-pair bit
__device__ __forceinline__ void swp16(unsigned &a, unsigned &b) {
  uint2v r = __builtin_amdgcn_permlane16_swap(a, b, false, false);
  a = r.x; b = r.y;
}
__device__ __forceinline__ float redq_sum(float v) {   // reduce lane bits 4,5
  uint2v r = __builtin_amdgcn_permlane16_swap(__float_as_uint(v), __float_as_uint(v), false, false);
  v = __uint_as_float(r.x) + __uint_as_float(r.y);
  r = __builtin_amdgcn_permlane32_swap(__float_as_uint(v), __float_as_uint(v), false, false);
  return __uint_as_float(r.x) + __uint_as_float(r.y);
}
__device__ __forceinline__ float red5_sum(float v) {   // bits 3,4,5
  v += __shfl_xor(v, 8);
  return redq_sum(v);
}

// prep: W_qkv -> bf16 ; Wout' = W∘γ -> bf16 ; bo' = bo∘γ.
__global__ __launch_bounds__(64) void prep(
    const float* __restrict__ wq, const float* __restrict__ wo,
    const float* __restrict__ gm, const float* __restrict__ bo,
    unsigned short* __restrict__ wbf, float* __restrict__ boG) {
  int d = blockIdx.x, lane = threadIdx.x;
  if (d < 768) {
    float4 wv = *(const float4*)(wq + (size_t)d * 256 + lane * 4);
    us4 o;
    o.x = f2b(wv.x); o.y = f2b(wv.y); o.z = f2b(wv.z); o.w = f2b(wv.w);
    *(us4*)(wbf + (size_t)d * 256 + lane * 4) = o;
  } else {
    int dd = d - 768;
    float g = gm[dd];
    float4 wv = *(const float4*)(wo + (size_t)dd * 256 + lane * 4);
    us4 o;
    o.x = f2b(wv.x * g); o.y = f2b(wv.y * g); o.z = f2b(wv.z * g); o.w = f2b(wv.w * g);
    *(us4*)(wbf + 196608 + (size_t)dd * 256 + lane * 4) = o;
    if (lane == 0) boG[dd] = bo[dd] * g;
  }
}

// One workgroup (512 thr, 8 waves) per window; wave w = head w.
// LDS: ldsX [64][264] bf16 = x_norm (LN at staging; later attn-out).
// Q+K merged; softmax without max-subtraction; ALL biases folded into MFMA
// acc-init; s_setprio(1) around every MFMA cluster (T5 — waves in different
// phases arbitrate for the matrix pipe). 3 barriers, no spills.
__global__ __launch_bounds__(512, 4) void grid_attn(
    const float* __restrict__ x,
    const float* __restrict__ lnw4,
    const float* __restrict__ lnb4,
    const unsigned short* __restrict__ Wqkv,
    const float* __restrict__ bqkv,
    const unsigned short* __restrict__ Wout,
    const float* __restrict__ boG,
    float* __restrict__ out) {

  __shared__ unsigned short ldsX[64 * 264];
  __shared__ float ldsMu[64];
  __shared__ float ldsRs[64];

  const int tid = threadIdx.x;
  const int w   = tid >> 6;      // wave = head
  const int lid = tid & 63;
  const int l16 = lid & 15;
  const int lhi = lid >> 4;

  const int n  = blockIdx.x;
  const int b  = n >> 8;
  const int wi = (n >> 4) & 15;
  const int wj = n & 15;

  // ---------- load raw x, stats butterfly, normalize, stage x_norm bf16 ----------
  {
    float4 v[8];
    float2 p[8];
    #pragma unroll
    for (int t = 0; t < 8; ++t) {
      int l = w * 8 + t;
      int a = l >> 3, cg = l & 7;
      int hh = a * 16 + wi, ww = cg * 16 + wj;
      v[t] = *(const float4*)(x + ((size_t)((b * 128 + hh) * 128 + ww)) * 256 + lid * 4);
      p[t].x = v[t].x + v[t].y + v[t].z + v[t].w;
      p[t].y = v[t].x * v[t].x + v[t].y * v[t].y + v[t].z * v[t].z + v[t].w * v[t].w;
    }
    const int h1 = lid & 1, h2 = (lid >> 1) & 1, h4 = (lid >> 2) & 1;
    float2 q[4];
    #pragma unroll
    for (int i = 0; i < 4; ++i) {
      float sx = h1 ? p[i].x : p[i + 4].x, sy = h1 ? p[i].y : p[i + 4].y;
      float kx = h1 ? p[i + 4].x : p[i].x, ky = h1 ? p[i + 4].y : p[i].y;
      q[i].x = kx + __shfl_xor(sx, 1);
      q[i].y = ky + __shfl_xor(sy, 1);
    }
    float2 r2[2];
    #pragma unroll
    for (int i = 0; i < 2; ++i) {
      float sx = h2 ? q[i].x : q[i + 2].x, sy = h2 ? q[i].y : q[i + 2].y;
      float kx = h2 ? q[i + 2].x : q[i].x, ky = h2 ? q[i + 2].y : q[i].y;
      r2[i].x = kx + __shfl_xor(sx, 2);
      r2[i].y = ky + __shfl_xor(sy, 2);
    }
    float fx, fy;
    {
      float sx = h4 ? r2[0].x : r2[1].x, sy = h4 ? r2[0].y : r2[1].y;
      float kx = h4 ? r2[1].x : r2[0].x, ky = h4 ? r2[1].y : r2[0].y;
      fx = kx + __shfl_xor(sx, 4);
      fy = ky + __shfl_xor(sy, 4);
    }
    fx = red5_sum(fx);
    fy = red5_sum(fy);
    if (lid < 8) {
      int T = h1 * 4 + h2 * 2 + h4;          // bit-reversed token slot
      float mu = fx * (1.0f / 256.0f);
      float var = fy * (1.0f / 256.0f) - mu * mu;
      ldsMu[w * 8 + T] = mu;
      ldsRs[w * 8 + T] = rsqrtf(var + 1e-5f);
    }
    float4 lw = *(const float4*)(lnw4 + lid * 4);
    float4 lb = *(const float4*)(lnb4 + lid * 4);
    #pragma unroll
    for (int t = 0; t < 8; ++t) {
      int l = w * 8 + t;
      float mu = ldsMu[w * 8 + t];      // wave-private broadcast reads
      float rs = ldsRs[w * 8 + t];
      float n0 = (v[t].x - mu) * rs * lw.x + lb.x;
      float n1 = (v[t].y - mu) * rs * lw.y + lb.y;
      float n2 = (v[t].z - mu) * rs * lw.z + lb.z;
      float n3 = (v[t].w - mu) * rs * lw.w + lb.w;
      uint2v o; o.x = pkbf(n0, n1); o.y = pkbf(n2, n3);
      *(uint2v*)(&ldsX[l * 264 + lid * 4]) = o;
    }
  }
  __syncthreads();

  // ---------- V GEMM: v = x_norm · Wv^T + bv (acc-init), transpose -> vtf ----------
  short8 vtf[2][2];
  {
    float bv0 = bqkv[512 + w * 32 + l16];
    float bv1 = bqkv[512 + w * 32 + 16 + l16];
    f32x4 va[4][2];
    #pragma unroll
    for (int tt = 0; tt < 4; ++tt) {
      va[tt][0] = (f32x4){bv0, bv0, bv0, bv0};
      va[tt][1] = (f32x4){bv1, bv1, bv1, bv1};
    }
    const unsigned short* wvp = Wqkv + (size_t)(512 + w * 32 + l16) * 256 + lhi * 8;
    __builtin_amdgcn_s_setprio(1);
    #pragma unroll 4
    for (int kc = 0; kc < 8; ++kc) {
      short8 wv0 = *(const short8*)(wvp + kc * 32);
      short8 wv1 = *(const short8*)(wvp + 16 * 256 + kc * 32);
      #pragma unroll
      for (int tt = 0; tt < 4; ++tt) {
        short8 xf = *(const short8*)(&ldsX[(tt * 16 + l16) * 264 + kc * 32 + lhi * 8]);
        va[tt][0] = __builtin_amdgcn_mfma_f32_16x16x32_bf16(xf, wv0, va[tt][0], 0, 0, 0);
        va[tt][1] = __builtin_amdgcn_mfma_f32_16x16x32_bf16(xf, wv1, va[tt][1], 0, 0, 0);
      }
    }
    __builtin_amdgcn_s_setprio(0);
    #pragma unroll
    for (int dt = 0; dt < 2; ++dt) {
      unsigned bu[8];
      #pragma unroll
      for (int tt = 0; tt < 4; ++tt) {
        bu[tt * 2]     = pkbf(va[tt][dt][0], va[tt][dt][1]);
        bu[tt * 2 + 1] = pkbf(va[tt][dt][2], va[tt][dt][3]);
      }
      swp32(bu[0], bu[2]); swp32(bu[1], bu[3]); swp32(bu[4], bu[6]); swp32(bu[5], bu[7]);
      swp16(bu[0], bu[2]); swp16(bu[1], bu[3]); swp16(bu[4], bu[6]); swp16(bu[5], bu[7]);
      U8 z0, z1;
      z0.u[0] = bu[0]; z0.u[1] = bu[1]; z0.u[2] = bu[2]; z0.u[3] = bu[3];
      z1.u[0] = bu[4]; z1.u[1] = bu[5]; z1.u[2] = bu[6]; z1.u[3] = bu[7];
      vtf[dt][0] = z0.s;
      vtf[dt][1] = z1.s;
    }
  }

  short8 qf[4], kf[4];

  // ---------- merged Q+K GEMM: xf read once -> 16 MFMA per kc ----------
  {
    f32x4 Cq0 = *(const f32x4*)(bqkv + w * 32 + lhi * 4);
    f32x4 Cq1 = *(const f32x4*)(bqkv + w * 32 + 16 + lhi * 4);
    f32x4 Ck0 = *(const f32x4*)(bqkv + 256 + w * 32 + lhi * 4);
    f32x4 Ck1 = *(const f32x4*)(bqkv + 256 + w * 32 + 16 + lhi * 4);
    f32x4 qa[2][4], ka[2][4];
    #pragma unroll
    for (int tt = 0; tt < 4; ++tt) {
      qa[0][tt] = Cq0; qa[1][tt] = Cq1;
      ka[0][tt] = Ck0; ka[1][tt] = Ck1;
    }
    const unsigned short* wqp = Wqkv + (size_t)(w * 32 + l16) * 256 + lhi * 8;
    const unsigned short* wkp = wqp + 256 * 256;
    __builtin_amdgcn_s_setprio(1);
    #pragma unroll 2
    for (int kc = 0; kc < 8; ++kc) {
      short8 wq0 = *(const short8*)(wqp + kc * 32);
      short8 wq1 = *(const short8*)(wqp + 16 * 256 + kc * 32);
      short8 wk0 = *(const short8*)(wkp + kc * 32);
      short8 wk1 = *(const short8*)(wkp + 16 * 256 + kc * 32);
      #pragma unroll
      for (int tt = 0; tt < 4; ++tt) {
        short8 xf = *(const short8*)(&ldsX[(tt * 16 + l16) * 264 + kc * 32 + lhi * 8]);
        qa[0][tt] = __builtin_amdgcn_mfma_f32_16x16x32_bf16(wq0, xf, qa[0][tt], 0, 0, 0);
        qa[1][tt] = __builtin_amdgcn_mfma_f32_16x16x32_bf16(wq1, xf, qa[1][tt], 0, 0, 0);
        ka[0][tt] = __builtin_amdgcn_mfma_f32_16x16x32_bf16(wk0, xf, ka[0][tt], 0, 0, 0);
        ka[1][tt] = __builtin_amdgcn_mfma_f32_16x16x32_bf16(wk1, xf, ka[1][tt], 0, 0, 0);
      }
    }
    __builtin_amdgcn_s_setprio(0);
    #pragma unroll
    for (int tt = 0; tt < 4; ++tt) {
      unsigned a0 = pkbf(qa[0][tt][0], qa[0][tt][1]), a1 = pkbf(qa[0][tt][2], qa[0][tt][3]);
      unsigned a2 = pkbf(qa[1][tt][0], qa[1][tt][1]), a3 = pkbf(qa[1][tt][2], qa[1][tt][3]);
      swp32(a0, a2); swp32(a1, a3);
      swp16(a0, a2); swp16(a1, a3);
      U8 z; z.u[0] = a0; z.u[1] = a1; z.u[2] = a2; z.u[3] = a3;
      qf[tt] = z.s;
      unsigned c0 = pkbf(ka[0][tt][0], ka[0][tt][1]), c1 = pkbf(ka[0][tt][2], ka[0][tt][3]);
      unsigned c2 = pkbf(ka[1][tt][0], ka[1][tt][1]), c3 = pkbf(ka[1][tt][2], ka[1][tt][3]);
      swp32(c0, c2); swp32(c1, c3);
      swp16(c0, c2); swp16(c1, c3);
      U8 y; y.u[0] = c0; y.u[1] = c1; y.u[2] = c2; y.u[3] = c3;
      kf[tt] = y.s;
    }
  }

  // ---------- fused scores + softmax (no max-subtraction) + PV per q-block ----------
  uint2v po[4][2];
  const float K2 = 0.25503487013594137f;   // (1/sqrt(32)) * log2(e)
  #pragma unroll
  for (int nn = 0; nn < 4; ++nn) {
    f32x4 s[4];
    __builtin_amdgcn_s_setprio(1);
    #pragma unroll
    for (int m = 0; m < 4; ++m)
      s[m] = __builtin_amdgcn_mfma_f32_16x16x32_bf16(kf[m], qf[nn], (f32x4){0.f,0.f,0.f,0.f}, 0, 0, 0);
    __builtin_amdgcn_s_setprio(0);
    float sm[4];
    unsigned bu[8];
    #pragma unroll
    for (int m = 0; m < 4; ++m) {
      float e0 = exp2f(s[m][0] * K2);
      float e1 = exp2f(s[m][1] * K2);
      float e2 = exp2f(s[m][2] * K2);
      float e3 = exp2f(s[m][3] * K2);
      sm[m] = (e0 + e1) + (e2 + e3);
      bu[m * 2]     = pkbf(e0, e1);
      bu[m * 2 + 1] = pkbf(e2, e3);
    }
    float sum = (sm[0] + sm[1]) + (sm[2] + sm[3]);
    sum = redq_sum(sum);
    float iv = 1.0f / sum;
    swp32(bu[0], bu[2]); swp32(bu[1], bu[3]); swp32(bu[4], bu[6]); swp32(bu[5], bu[7]);
    swp16(bu[0], bu[2]); swp16(bu[1], bu[3]); swp16(bu[4], bu[6]); swp16(bu[5], bu[7]);
    U8 z0, z1;
    z0.u[0] = bu[0]; z0.u[1] = bu[1]; z0.u[2] = bu[2]; z0.u[3] = bu[3];
    z1.u[0] = bu[4]; z1.u[1] = bu[5]; z1.u[2] = bu[6]; z1.u[3] = bu[7];
    f32x4 ot0 = (f32x4){0.f,0.f,0.f,0.f};
    f32x4 ot1 = (f32x4){0.f,0.f,0.f,0.f};
    __builtin_amdgcn_s_setprio(1);
    ot0 = __builtin_amdgcn_mfma_f32_16x16x32_bf16(vtf[0][0], z0.s, ot0, 0, 0, 0);
    ot0 = __builtin_amdgcn_mfma_f32_16x16x32_bf16(vtf[0][1], z1.s, ot0, 0, 0, 0);
    ot1 = __builtin_amdgcn_mfma_f32_16x16x32_bf16(vtf[1][0], z0.s, ot1, 0, 0, 0);
    ot1 = __builtin_amdgcn_mfma_f32_16x16x32_bf16(vtf[1][1], z1.s, ot1, 0, 0, 0);
    __builtin_amdgcn_s_setprio(0);
    po[nn][0].x = pkbf(ot0[0] * iv, ot0[1] * iv);
    po[nn][0].y = pkbf(ot0[2] * iv, ot0[3] * iv);
    po[nn][1].x = pkbf(ot1[0] * iv, ot1[1] * iv);
    po[nn][1].y = pkbf(ot1[2] * iv, ot1[3] * iv);
  }

  __syncthreads();   // all x_norm reads done before overwrite

  // ---------- stage attention-out (bf16) into ldsX ----------
  #pragma unroll
  for (int nn = 0; nn < 4; ++nn)
    #pragma unroll
    for (int dt = 0; dt < 2; ++dt)
      *(uint2v*)(&ldsX[(nn * 16 + l16) * 264 + w * 32 + dt * 16 + lhi * 4]) = po[nn][dt];
  __syncthreads();

  // ---------- out_proj: Y = A_out · Wout'^T + bo∘γ (acc-init); channels [32w,32w+32) ----------
  float ob0 = boG[w * 32 + l16];
  float ob1 = boG[w * 32 + 16 + l16];
  f32x4 ya[4][2];
  #pragma unroll
  for (int mt = 0; mt < 4; ++mt) {
    ya[mt][0] = (f32x4){ob0, ob0, ob0, ob0};
    ya[mt][1] = (f32x4){ob1, ob1, ob1, ob1};
  }
  {
    const unsigned short* wop = Wout + (size_t)(w * 32 + l16) * 256 + lhi * 8;
    __builtin_amdgcn_s_setprio(1);
    #pragma unroll 4
    for (int kc = 0; kc < 8; ++kc) {
      short8 wf0 = *(const short8*)(wop + kc * 32);
      short8 wf1 = *(const short8*)(wop + 16 * 256 + kc * 32);
      #pragma unroll
      for (int mt = 0; mt < 4; ++mt) {
        short8 af = *(const short8*)(&ldsX[(mt * 16 + l16) * 264 + kc * 32 + lhi * 8]);
        ya[mt][0] = __builtin_amdgcn_mfma_f32_16x16x32_bf16(af, wf0, ya[mt][0], 0, 0, 0);
        ya[mt][1] = __builtin_amdgcn_mfma_f32_16x16x32_bf16(af, wf1, ya[mt][1], 0, 0, 0);
      }
    }
    __builtin_amdgcn_s_setprio(0);
  }

  // ---------- epilogue: scatter (biases already in accumulators) ----------
  #pragma unroll
  for (int mt = 0; mt < 4; ++mt)
    #pragma unroll
    for (int r = 0; r < 4; ++r) {
      int row = mt * 16 + lhi * 4 + r;
      int a = row >> 3, cg = row & 7;
      int hh = a * 16 + wi, ww2 = cg * 16 + wj;
      float* pout = out + ((size_t)((b * 128 + hh) * 128 + ww2)) * 256 + w * 32;
      pout[l16]      = ya[mt][0][r];
      pout[l16 + 16] = ya[mt][1][r];
    }
}

extern "C" void kernel_launch(void* const* d_in, const int* in_sizes, int n_in,
                              void* d_out, int out_size, void* d_ws, size_t ws_size,
                              hipStream_t stream) {
  const float* x    = (const float*)d_in[0];
  const float* ln_w = (const float*)d_in[1];
  const float* ln_b = (const float*)d_in[2];
  const float* ipw  = (const float*)d_in[3];
  const float* ipb  = (const float*)d_in[4];
  const float* opw  = (const float*)d_in[5];
  const float* opb  = (const float*)d_in[6];
  const float* gm   = (const float*)d_in[7];

  unsigned short* wbf = (unsigned short*)d_ws;          // [0,196608) Wqkv bf16 ; [196608,262144) Wout∘γ bf16
  float* boG = (float*)(wbf + 262144);                  // [256]

  prep<<<1024, 64, 0, stream>>>(ipw, opw, gm, opb, wbf, boG);
  grid_attn<<<4096, 512, 0, stream>>>(x, ln_w, ln_b, wbf, ipb,
                                      wbf + 196608, boG, (float*)d_out);
}

// Round 13
// 320.698 us; speedup vs baseline: 1.0067x; 1.0067x over previous
//
#include <hip/hip_runtime.h>
#include <hip/hip_bf16.h>

typedef __attribute__((ext_vector_type(8))) short short8;
typedef __attribute__((ext_vector_type(4))) float f32x4;
typedef __attribute__((ext_vector_type(4))) unsigned short us4;
typedef __attribute__((ext_vector_type(2))) unsigned uint2v;

union U8 { unsigned u[4]; short8 s; };

__device__ __forceinline__ unsigned short f2b(float f) {
  unsigned u = __float_as_uint(f);
  u += 0x7FFFu + ((u >> 16) & 1u);
  return (unsigned short)(u >> 16);
}
__device__ __forceinline__ unsigned pkbf(float lo, float hi) {
  __hip_bfloat162 h = __float22bfloat162_rn(make_float2(lo, hi));
  unsigned u; __builtin_memcpy(&u, &h, 4);
  return u;
}
// exchange lane bit5 with the (a,b) register-pair bit  (a=vdst, b=vsrc)
__device__ __forceinline__ void swp32(unsigned &a, unsigned &b) {
  uint2v r = __builtin_amdgcn_permlane32_swap(a, b, false, false);
  a = r.x; b = r.y;
}
// exchange lane bit4 with the (a,b) register-pair bit
__device__ __forceinline__ void swp16(unsigned &a, unsigned &b) {
  uint2v r = __builtin_amdgcn_permlane16_swap(a, b, false, false);
  a = r.x; b = r.y;
}
__device__ __forceinline__ float redq_sum(float v) {   // reduce lane bits 4,5
  uint2v r = __builtin_amdgcn_permlane16_swap(__float_as_uint(v), __float_as_uint(v), false, false);
  v = __uint_as_float(r.x) + __uint_as_float(r.y);
  r = __builtin_amdgcn_permlane32_swap(__float_as_uint(v), __float_as_uint(v), false, false);
  return __uint_as_float(r.x) + __uint_as_float(r.y);
}
__device__ __forceinline__ float red5_sum(float v) {   // bits 3,4,5
  v += __shfl_xor(v, 8);
  return redq_sum(v);
}

// prep: W_qkv -> bf16 ; Wout' = W∘γ -> bf16 ; bo' = bo∘γ.
__global__ __launch_bounds__(64) void prep(
    const float* __restrict__ wq, const float* __restrict__ wo,
    const float* __restrict__ gm, const float* __restrict__ bo,
    unsigned short* __restrict__ wbf, float* __restrict__ boG) {
  int d = blockIdx.x, lane = threadIdx.x;
  if (d < 768) {
    float4 wv = *(const float4*)(wq + (size_t)d * 256 + lane * 4);
    us4 o;
    o.x = f2b(wv.x); o.y = f2b(wv.y); o.z = f2b(wv.z); o.w = f2b(wv.w);
    *(us4*)(wbf + (size_t)d * 256 + lane * 4) = o;
  } else {
    int dd = d - 768;
    float g = gm[dd];
    float4 wv = *(const float4*)(wo + (size_t)dd * 256 + lane * 4);
    us4 o;
    o.x = f2b(wv.x * g); o.y = f2b(wv.y * g); o.z = f2b(wv.z * g); o.w = f2b(wv.w * g);
    *(us4*)(wbf + 196608 + (size_t)dd * 256 + lane * 4) = o;
    if (lane == 0) boG[dd] = bo[dd] * g;
  }
}

// One workgroup (512 thr, 8 waves) per window; wave w = head w.
// LDS: ldsX [64][264] x_norm bf16 (read-only after LN) + ldsY [64][264]
// attention-out bf16 (separate buffer -> no overwrite hazard). Only TWO
// barriers: after LN staging, after attn-out staging. Attention output is
// written to ldsY immediately per column-block (no register-held po array).
__global__ __launch_bounds__(512, 4) void grid_attn(
    const float* __restrict__ x,
    const float* __restrict__ lnw4,
    const float* __restrict__ lnb4,
    const unsigned short* __restrict__ Wqkv,
    const float* __restrict__ bqkv,
    const unsigned short* __restrict__ Wout,
    const float* __restrict__ boG,
    float* __restrict__ out) {

  __shared__ unsigned short ldsX[64 * 264];
  __shared__ unsigned short ldsY[64 * 264];
  __shared__ float ldsMu[64];
  __shared__ float ldsRs[64];

  const int tid = threadIdx.x;
  const int w   = tid >> 6;      // wave = head
  const int lid = tid & 63;
  const int l16 = lid & 15;
  const int lhi = lid >> 4;

  const int n  = blockIdx.x;
  const int b  = n >> 8;
  const int wi = (n >> 4) & 15;
  const int wj = n & 15;

  // ---------- load raw x, stats butterfly, normalize, stage x_norm bf16 ----------
  {
    float4 v[8];
    float2 p[8];
    #pragma unroll
    for (int t = 0; t < 8; ++t) {
      int l = w * 8 + t;
      int a = l >> 3, cg = l & 7;
      int hh = a * 16 + wi, ww = cg * 16 + wj;
      v[t] = *(const float4*)(x + ((size_t)((b * 128 + hh) * 128 + ww)) * 256 + lid * 4);
      p[t].x = v[t].x + v[t].y + v[t].z + v[t].w;
      p[t].y = v[t].x * v[t].x + v[t].y * v[t].y + v[t].z * v[t].z + v[t].w * v[t].w;
    }
    const int h1 = lid & 1, h2 = (lid >> 1) & 1, h4 = (lid >> 2) & 1;
    float2 q[4];
    #pragma unroll
    for (int i = 0; i < 4; ++i) {
      float sx = h1 ? p[i].x : p[i + 4].x, sy = h1 ? p[i].y : p[i + 4].y;
      float kx = h1 ? p[i + 4].x : p[i].x, ky = h1 ? p[i + 4].y : p[i].y;
      q[i].x = kx + __shfl_xor(sx, 1);
      q[i].y = ky + __shfl_xor(sy, 1);
    }
    float2 r2[2];
    #pragma unroll
    for (int i = 0; i < 2; ++i) {
      float sx = h2 ? q[i].x : q[i + 2].x, sy = h2 ? q[i].y : q[i + 2].y;
      float kx = h2 ? q[i + 2].x : q[i].x, ky = h2 ? q[i + 2].y : q[i].y;
      r2[i].x = kx + __shfl_xor(sx, 2);
      r2[i].y = ky + __shfl_xor(sy, 2);
    }
    float fx, fy;
    {
      float sx = h4 ? r2[0].x : r2[1].x, sy = h4 ? r2[0].y : r2[1].y;
      float kx = h4 ? r2[1].x : r2[0].x, ky = h4 ? r2[1].y : r2[0].y;
      fx = kx + __shfl_xor(sx, 4);
      fy = ky + __shfl_xor(sy, 4);
    }
    fx = red5_sum(fx);
    fy = red5_sum(fy);
    if (lid < 8) {
      int T = h1 * 4 + h2 * 2 + h4;          // bit-reversed token slot
      float mu = fx * (1.0f / 256.0f);
      float var = fy * (1.0f / 256.0f) - mu * mu;
      ldsMu[w * 8 + T] = mu;
      ldsRs[w * 8 + T] = rsqrtf(var + 1e-5f);
    }
    float4 lw = *(const float4*)(lnw4 + lid * 4);
    float4 lb = *(const float4*)(lnb4 + lid * 4);
    #pragma unroll
    for (int t = 0; t < 8; ++t) {
      int l = w * 8 + t;
      float mu = ldsMu[w * 8 + t];      // wave-private broadcast reads
      float rs = ldsRs[w * 8 + t];
      float n0 = (v[t].x - mu) * rs * lw.x + lb.x;
      float n1 = (v[t].y - mu) * rs * lw.y + lb.y;
      float n2 = (v[t].z - mu) * rs * lw.z + lb.z;
      float n3 = (v[t].w - mu) * rs * lw.w + lb.w;
      uint2v o; o.x = pkbf(n0, n1); o.y = pkbf(n2, n3);
      *(uint2v*)(&ldsX[l * 264 + lid * 4]) = o;
    }
  }
  __syncthreads();

  // ---------- V GEMM: v = x_norm · Wv^T + bv (acc-init), transpose -> vtf ----------
  short8 vtf[2][2];
  {
    float bv0 = bqkv[512 + w * 32 + l16];
    float bv1 = bqkv[512 + w * 32 + 16 + l16];
    f32x4 va[4][2];
    #pragma unroll
    for (int tt = 0; tt < 4; ++tt) {
      va[tt][0] = (f32x4){bv0, bv0, bv0, bv0};
      va[tt][1] = (f32x4){bv1, bv1, bv1, bv1};
    }
    const unsigned short* wvp = Wqkv + (size_t)(512 + w * 32 + l16) * 256 + lhi * 8;
    __builtin_amdgcn_s_setprio(1);
    #pragma unroll 4
    for (int kc = 0; kc < 8; ++kc) {
      short8 wv0 = *(const short8*)(wvp + kc * 32);
      short8 wv1 = *(const short8*)(wvp + 16 * 256 + kc * 32);
      #pragma unroll
      for (int tt = 0; tt < 4; ++tt) {
        short8 xf = *(const short8*)(&ldsX[(tt * 16 + l16) * 264 + kc * 32 + lhi * 8]);
        va[tt][0] = __builtin_amdgcn_mfma_f32_16x16x32_bf16(xf, wv0, va[tt][0], 0, 0, 0);
        va[tt][1] = __builtin_amdgcn_mfma_f32_16x16x32_bf16(xf, wv1, va[tt][1], 0, 0, 0);
      }
    }
    __builtin_amdgcn_s_setprio(0);
    #pragma unroll
    for (int dt = 0; dt < 2; ++dt) {
      unsigned bu[8];
      #pragma unroll
      for (int tt = 0; tt < 4; ++tt) {
        bu[tt * 2]     = pkbf(va[tt][dt][0], va[tt][dt][1]);
        bu[tt * 2 + 1] = pkbf(va[tt][dt][2], va[tt][dt][3]);
      }
      swp32(bu[0], bu[2]); swp32(bu[1], bu[3]); swp32(bu[4], bu[6]); swp32(bu[5], bu[7]);
      swp16(bu[0], bu[2]); swp16(bu[1], bu[3]); swp16(bu[4], bu[6]); swp16(bu[5], bu[7]);
      U8 z0, z1;
      z0.u[0] = bu[0]; z0.u[1] = bu[1]; z0.u[2] = bu[2]; z0.u[3] = bu[3];
      z1.u[0] = bu[4]; z1.u[1] = bu[5]; z1.u[2] = bu[6]; z1.u[3] = bu[7];
      vtf[dt][0] = z0.s;
      vtf[dt][1] = z1.s;
    }
  }

  short8 qf[4], kf[4];

  // ---------- merged Q+K GEMM: xf read once -> 16 MFMA per kc ----------
  {
    f32x4 Cq0 = *(const f32x4*)(bqkv + w * 32 + lhi * 4);
    f32x4 Cq1 = *(const f32x4*)(bqkv + w * 32 + 16 + lhi * 4);
    f32x4 Ck0 = *(const f32x4*)(bqkv + 256 + w * 32 + lhi * 4);
    f32x4 Ck1 = *(const f32x4*)(bqkv + 256 + w * 32 + 16 + lhi * 4);
    f32x4 qa[2][4], ka[2][4];
    #pragma unroll
    for (int tt = 0; tt < 4; ++tt) {
      qa[0][tt] = Cq0; qa[1][tt] = Cq1;
      ka[0][tt] = Ck0; ka[1][tt] = Ck1;
    }
    const unsigned short* wqp = Wqkv + (size_t)(w * 32 + l16) * 256 + lhi * 8;
    const unsigned short* wkp = wqp + 256 * 256;
    __builtin_amdgcn_s_setprio(1);
    #pragma unroll 2
    for (int kc = 0; kc < 8; ++kc) {
      short8 wq0 = *(const short8*)(wqp + kc * 32);
      short8 wq1 = *(const short8*)(wqp + 16 * 256 + kc * 32);
      short8 wk0 = *(const short8*)(wkp + kc * 32);
      short8 wk1 = *(const short8*)(wkp + 16 * 256 + kc * 32);
      #pragma unroll
      for (int tt = 0; tt < 4; ++tt) {
        short8 xf = *(const short8*)(&ldsX[(tt * 16 + l16) * 264 + kc * 32 + lhi * 8]);
        qa[0][tt] = __builtin_amdgcn_mfma_f32_16x16x32_bf16(wq0, xf, qa[0][tt], 0, 0, 0);
        qa[1][tt] = __builtin_amdgcn_mfma_f32_16x16x32_bf16(wq1, xf, qa[1][tt], 0, 0, 0);
        ka[0][tt] = __builtin_amdgcn_mfma_f32_16x16x32_bf16(wk0, xf, ka[0][tt], 0, 0, 0);
        ka[1][tt] = __builtin_amdgcn_mfma_f32_16x16x32_bf16(wk1, xf, ka[1][tt], 0, 0, 0);
      }
    }
    __builtin_amdgcn_s_setprio(0);
    #pragma unroll
    for (int tt = 0; tt < 4; ++tt) {
      unsigned a0 = pkbf(qa[0][tt][0], qa[0][tt][1]), a1 = pkbf(qa[0][tt][2], qa[0][tt][3]);
      unsigned a2 = pkbf(qa[1][tt][0], qa[1][tt][1]), a3 = pkbf(qa[1][tt][2], qa[1][tt][3]);
      swp32(a0, a2); swp32(a1, a3);
      swp16(a0, a2); swp16(a1, a3);
      U8 z; z.u[0] = a0; z.u[1] = a1; z.u[2] = a2; z.u[3] = a3;
      qf[tt] = z.s;
      unsigned c0 = pkbf(ka[0][tt][0], ka[0][tt][1]), c1 = pkbf(ka[0][tt][2], ka[0][tt][3]);
      unsigned c2 = pkbf(ka[1][tt][0], ka[1][tt][1]), c3 = pkbf(ka[1][tt][2], ka[1][tt][3]);
      swp32(c0, c2); swp32(c1, c3);
      swp16(c0, c2); swp16(c1, c3);
      U8 y; y.u[0] = c0; y.u[1] = c1; y.u[2] = c2; y.u[3] = c3;
      kf[tt] = y.s;
    }
  }

  // ---------- fused scores + softmax (no max-sub) + PV; store to ldsY per block ----------
  const float K2 = 0.25503487013594137f;   // (1/sqrt(32)) * log2(e)
  #pragma unroll
  for (int nn = 0; nn < 4; ++nn) {
    f32x4 s[4];
    __builtin_amdgcn_s_setprio(1);
    #pragma unroll
    for (int m = 0; m < 4; ++m)
      s[m] = __builtin_amdgcn_mfma_f32_16x16x32_bf16(kf[m], qf[nn], (f32x4){0.f,0.f,0.f,0.f}, 0, 0, 0);
    __builtin_amdgcn_s_setprio(0);
    float sm[4];
    unsigned bu[8];
    #pragma unroll
    for (int m = 0; m < 4; ++m) {
      float e0 = exp2f(s[m][0] * K2);
      float e1 = exp2f(s[m][1] * K2);
      float e2 = exp2f(s[m][2] * K2);
      float e3 = exp2f(s[m][3] * K2);
      sm[m] = (e0 + e1) + (e2 + e3);
      bu[m * 2]     = pkbf(e0, e1);
      bu[m * 2 + 1] = pkbf(e2, e3);
    }
    float sum = (sm[0] + sm[1]) + (sm[2] + sm[3]);
    sum = redq_sum(sum);
    float iv = 1.0f / sum;
    swp32(bu[0], bu[2]); swp32(bu[1], bu[3]); swp32(bu[4], bu[6]); swp32(bu[5], bu[7]);
    swp16(bu[0], bu[2]); swp16(bu[1], bu[3]); swp16(bu[4], bu[6]); swp16(bu[5], bu[7]);
    U8 z0, z1;
    z0.u[0] = bu[0]; z0.u[1] = bu[1]; z0.u[2] = bu[2]; z0.u[3] = bu[3];
    z1.u[0] = bu[4]; z1.u[1] = bu[5]; z1.u[2] = bu[6]; z1.u[3] = bu[7];
    f32x4 ot0 = (f32x4){0.f,0.f,0.f,0.f};
    f32x4 ot1 = (f32x4){0.f,0.f,0.f,0.f};
    __builtin_amdgcn_s_setprio(1);
    ot0 = __builtin_amdgcn_mfma_f32_16x16x32_bf16(vtf[0][0], z0.s, ot0, 0, 0, 0);
    ot0 = __builtin_amdgcn_mfma_f32_16x16x32_bf16(vtf[0][1], z1.s, ot0, 0, 0, 0);
    ot1 = __builtin_amdgcn_mfma_f32_16x16x32_bf16(vtf[1][0], z0.s, ot1, 0, 0, 0);
    ot1 = __builtin_amdgcn_mfma_f32_16x16x32_bf16(vtf[1][1], z1.s, ot1, 0, 0, 0);
    __builtin_amdgcn_s_setprio(0);
    uint2v o0, o1;
    o0.x = pkbf(ot0[0] * iv, ot0[1] * iv);
    o0.y = pkbf(ot0[2] * iv, ot0[3] * iv);
    o1.x = pkbf(ot1[0] * iv, ot1[1] * iv);
    o1.y = pkbf(ot1[2] * iv, ot1[3] * iv);
    *(uint2v*)(&ldsY[(nn * 16 + l16) * 264 + w * 32 + lhi * 4]) = o0;
    *(uint2v*)(&ldsY[(nn * 16 + l16) * 264 + w * 32 + 16 + lhi * 4]) = o1;
  }

  __syncthreads();   // all attn-out staged in ldsY

  // ---------- out_proj: Y = A_out · Wout'^T + bo∘γ (acc-init); channels [32w,32w+32) ----------
  float ob0 = boG[w * 32 + l16];
  float ob1 = boG[w * 32 + 16 + l16];
  f32x4 ya[4][2];
  #pragma unroll
  for (int mt = 0; mt < 4; ++mt) {
    ya[mt][0] = (f32x4){ob0, ob0, ob0, ob0};
    ya[mt][1] = (f32x4){ob1, ob1, ob1, ob1};
  }
  {
    const unsigned short* wop = Wout + (size_t)(w * 32 + l16) * 256 + lhi * 8;
    __builtin_amdgcn_s_setprio(1);
    #pragma unroll 4
    for (int kc = 0; kc < 8; ++kc) {
      short8 wf0 = *(const short8*)(wop + kc * 32);
      short8 wf1 = *(const short8*)(wop + 16 * 256 + kc * 32);
      #pragma unroll
      for (int mt = 0; mt < 4; ++mt) {
        short8 af = *(const short8*)(&ldsY[(mt * 16 + l16) * 264 + kc * 32 + lhi * 8]);
        ya[mt][0] = __builtin_amdgcn_mfma_f32_16x16x32_bf16(af, wf0, ya[mt][0], 0, 0, 0);
        ya[mt][1] = __builtin_amdgcn_mfma_f32_16x16x32_bf16(af, wf1, ya[mt][1], 0, 0, 0);
      }
    }
    __builtin_amdgcn_s_setprio(0);
  }

  // ---------- epilogue: scatter (biases already in accumulators) ----------
  #pragma unroll
  for (int mt = 0; mt < 4; ++mt)
    #pragma unroll
    for (int r = 0; r < 4; ++r) {
      int row = mt * 16 + lhi * 4 + r;
      int a = row >> 3, cg = row & 7;
      int hh = a * 16 + wi, ww2 = cg * 16 + wj;
      float* pout = out + ((size_t)((b * 128 + hh) * 128 + ww2)) * 256 + w * 32;
      pout[l16]      = ya[mt][0][r];
      pout[l16 + 16] = ya[mt][1][r];
    }
}

extern "C" void kernel_launch(void* const* d_in, const int* in_sizes, int n_in,
                              void* d_out, int out_size, void* d_ws, size_t ws_size,
                              hipStream_t stream) {
  const float* x    = (const float*)d_in[0];
  const float* ln_w = (const float*)d_in[1];
  const float* ln_b = (const float*)d_in[2];
  const float* ipw  = (const float*)d_in[3];
  const float* ipb  = (const float*)d_in[4];
  const float* opw  = (const float*)d_in[5];
  const float* opb  = (const float*)d_in[6];
  const float* gm   = (const float*)d_in[7];

  unsigned short* wbf = (unsigned short*)d_ws;          // [0,196608) Wqkv bf16 ; [196608,262144) Wout∘γ bf16
  float* boG = (float*)(wbf + 262144);                  // [256]

  prep<<<1024, 64, 0, stream>>>(ipw, opw, gm, opb, wbf, boG);
  grid_attn<<<4096, 512, 0, stream>>>(x, ln_w, ln_b, wbf, ipb,
                                      wbf + 196608, boG, (float*)d_out);
}

// Round 14
// 313.698 us; speedup vs baseline: 1.0292x; 1.0223x over previous
//
#include <hip/hip_runtime.h>
#include <hip/hip_bf16.h>

typedef __attribute__((ext_vector_type(8))) short short8;
typedef __attribute__((ext_vector_type(4))) float f32x4;
typedef __attribute__((ext_vector_type(4))) unsigned short us4;
typedef __attribute__((ext_vector_type(2))) unsigned uint2v;

union U8 { unsigned u[4]; short8 s; };

__device__ __forceinline__ unsigned short f2b(float f) {
  unsigned u = __float_as_uint(f);
  u += 0x7FFFu + ((u >> 16) & 1u);
  return (unsigned short)(u >> 16);
}
__device__ __forceinline__ unsigned pkbf(float lo, float hi) {
  __hip_bfloat162 h = __float22bfloat162_rn(make_float2(lo, hi));
  unsigned u; __builtin_memcpy(&u, &h, 4);
  return u;
}
__device__ __forceinline__ void swp32(unsigned &a, unsigned &b) {
  uint2v r = __builtin_amdgcn_permlane32_swap(a, b, false, false);
  a = r.x; b = r.y;
}
__device__ __forceinline__ void swp16(unsigned &a, unsigned &b) {
  uint2v r = __builtin_amdgcn_permlane16_swap(a, b, false, false);
  a = r.x; b = r.y;
}
__device__ __forceinline__ float redq_sum(float v) {   // reduce lane bits 4,5
  uint2v r = __builtin_amdgcn_permlane16_swap(__float_as_uint(v), __float_as_uint(v), false, false);
  v = __uint_as_float(r.x) + __uint_as_float(r.y);
  r = __builtin_amdgcn_permlane32_swap(__float_as_uint(v), __float_as_uint(v), false, false);
  return __uint_as_float(r.x) + __uint_as_float(r.y);
}
__device__ __forceinline__ float red5_sum(float v) {   // bits 3,4,5
  v += __shfl_xor(v, 8);
  return redq_sum(v);
}

// prep: W_qkv -> bf16 ; Wout' = W∘γ -> bf16 ; bo' = bo∘γ.
__global__ __launch_bounds__(64) void prep(
    const float* __restrict__ wq, const float* __restrict__ wo,
    const float* __restrict__ gm, const float* __restrict__ bo,
    unsigned short* __restrict__ wbf, float* __restrict__ boG) {
  int d = blockIdx.x, lane = threadIdx.x;
  if (d < 768) {
    float4 wv = *(const float4*)(wq + (size_t)d * 256 + lane * 4);
    us4 o;
    o.x = f2b(wv.x); o.y = f2b(wv.y); o.z = f2b(wv.z); o.w = f2b(wv.w);
    *(us4*)(wbf + (size_t)d * 256 + lane * 4) = o;
  } else {
    int dd = d - 768;
    float g = gm[dd];
    float4 wv = *(const float4*)(wo + (size_t)dd * 256 + lane * 4);
    us4 o;
    o.x = f2b(wv.x * g); o.y = f2b(wv.y * g); o.z = f2b(wv.z * g); o.w = f2b(wv.w * g);
    *(us4*)(wbf + 196608 + (size_t)dd * 256 + lane * 4) = o;
    if (lane == 0) boG[dd] = bo[dd] * g;
  }
}

// One workgroup (512 thr, 8 waves) handles TWO windows (2n, 2n+1); wave = head.
// Cross-window pipelining: scores(A) [VALU-heavy] runs adjacent to V/QK(B)
// [MFMA/mem-heavy]; scores(B) adjacent to out_proj(A). Attention-out overwrites
// ldsX[v] (barrier-protected). LDS 68.6 KB -> still 2 blocks/CU (16 waves).
__global__ __launch_bounds__(512, 4) void grid_attn(
    const float* __restrict__ x,
    const float* __restrict__ lnw4,
    const float* __restrict__ lnb4,
    const unsigned short* __restrict__ Wqkv,
    const float* __restrict__ bqkv,
    const unsigned short* __restrict__ Wout,
    const float* __restrict__ boG,
    float* __restrict__ out) {

  __shared__ unsigned short ldsX[2][64 * 264];
  __shared__ float ldsMu[2][64];
  __shared__ float ldsRs[2][64];

  const int tid = threadIdx.x;
  const int w   = tid >> 6;      // wave = head
  const int lid = tid & 63;
  const int l16 = lid & 15;
  const int lhi = lid >> 4;

  const int n0 = blockIdx.x * 2;

  // per-window spatial coords
  int bA = n0 >> 8,      wiA = (n0 >> 4) & 15,       wjA = n0 & 15;
  int bB = (n0 + 1) >> 8, wiB = ((n0 + 1) >> 4) & 15, wjB = (n0 + 1) & 15;

  // ---------- LN for both windows (loads hoisted so HBM latency overlaps) ----------
  {
    float4 vA[8], vB[8];
    #pragma unroll
    for (int t = 0; t < 8; ++t) {
      int l = w * 8 + t;
      int a = l >> 3, cg = l & 7;
      vA[t] = *(const float4*)(x + ((size_t)((bA * 128 + a * 16 + wiA) * 128 + cg * 16 + wjA)) * 256 + lid * 4);
    }
    #pragma unroll
    for (int t = 0; t < 8; ++t) {
      int l = w * 8 + t;
      int a = l >> 3, cg = l & 7;
      vB[t] = *(const float4*)(x + ((size_t)((bB * 128 + a * 16 + wiB) * 128 + cg * 16 + wjB)) * 256 + lid * 4);
    }
    float4 lw = *(const float4*)(lnw4 + lid * 4);
    float4 lb = *(const float4*)(lnb4 + lid * 4);
    const int h1 = lid & 1, h2 = (lid >> 1) & 1, h4 = (lid >> 2) & 1;

    auto stats_norm = [&](float4 (&v)[8], int vv) {
      float2 p[8];
      #pragma unroll
      for (int t = 0; t < 8; ++t) {
        p[t].x = v[t].x + v[t].y + v[t].z + v[t].w;
        p[t].y = v[t].x * v[t].x + v[t].y * v[t].y + v[t].z * v[t].z + v[t].w * v[t].w;
      }
      float2 q[4];
      #pragma unroll
      for (int i = 0; i < 4; ++i) {
        float sx = h1 ? p[i].x : p[i + 4].x, sy = h1 ? p[i].y : p[i + 4].y;
        float kx = h1 ? p[i + 4].x : p[i].x, ky = h1 ? p[i + 4].y : p[i].y;
        q[i].x = kx + __shfl_xor(sx, 1);
        q[i].y = ky + __shfl_xor(sy, 1);
      }
      float2 r2[2];
      #pragma unroll
      for (int i = 0; i < 2; ++i) {
        float sx = h2 ? q[i].x : q[i + 2].x, sy = h2 ? q[i].y : q[i + 2].y;
        float kx = h2 ? q[i + 2].x : q[i].x, ky = h2 ? q[i + 2].y : q[i].y;
        r2[i].x = kx + __shfl_xor(sx, 2);
        r2[i].y = ky + __shfl_xor(sy, 2);
      }
      float fx, fy;
      {
        float sx = h4 ? r2[0].x : r2[1].x, sy = h4 ? r2[0].y : r2[1].y;
        float kx = h4 ? r2[1].x : r2[0].x, ky = h4 ? r2[1].y : r2[0].y;
        fx = kx + __shfl_xor(sx, 4);
        fy = ky + __shfl_xor(sy, 4);
      }
      fx = red5_sum(fx);
      fy = red5_sum(fy);
      if (lid < 8) {
        int T = h1 * 4 + h2 * 2 + h4;        // bit-reversed token slot
        float mu = fx * (1.0f / 256.0f);
        float var = fy * (1.0f / 256.0f) - mu * mu;
        ldsMu[vv][w * 8 + T] = mu;
        ldsRs[vv][w * 8 + T] = rsqrtf(var + 1e-5f);
      }
      #pragma unroll
      for (int t = 0; t < 8; ++t) {
        int l = w * 8 + t;
        float mu = ldsMu[vv][w * 8 + t];
        float rs = ldsRs[vv][w * 8 + t];
        float m0 = (v[t].x - mu) * rs * lw.x + lb.x;
        float m1 = (v[t].y - mu) * rs * lw.y + lb.y;
        float m2 = (v[t].z - mu) * rs * lw.z + lb.z;
        float m3 = (v[t].w - mu) * rs * lw.w + lb.w;
        uint2v o; o.x = pkbf(m0, m1); o.y = pkbf(m2, m3);
        *(uint2v*)(&ldsX[vv][l * 264 + lid * 4]) = o;
      }
    };
    stats_norm(vA, 0);
    stats_norm(vB, 1);
  }
  __syncthreads();   // bar1: x_norm staged for both windows

  // ---------- per-window phase lambdas ----------
  const float K2 = 0.25503487013594137f;   // (1/sqrt(32)) * log2(e)

  auto Vg = [&](const unsigned short* xb, short8 (&vtf)[2][2]) {
    float bv0 = bqkv[512 + w * 32 + l16];
    float bv1 = bqkv[512 + w * 32 + 16 + l16];
    f32x4 va[4][2];
    #pragma unroll
    for (int tt = 0; tt < 4; ++tt) {
      va[tt][0] = (f32x4){bv0, bv0, bv0, bv0};
      va[tt][1] = (f32x4){bv1, bv1, bv1, bv1};
    }
    const unsigned short* wvp = Wqkv + (size_t)(512 + w * 32 + l16) * 256 + lhi * 8;
    __builtin_amdgcn_s_setprio(1);
    #pragma unroll 4
    for (int kc = 0; kc < 8; ++kc) {
      short8 wv0 = *(const short8*)(wvp + kc * 32);
      short8 wv1 = *(const short8*)(wvp + 16 * 256 + kc * 32);
      #pragma unroll
      for (int tt = 0; tt < 4; ++tt) {
        short8 xf = *(const short8*)(&xb[(tt * 16 + l16) * 264 + kc * 32 + lhi * 8]);
        va[tt][0] = __builtin_amdgcn_mfma_f32_16x16x32_bf16(xf, wv0, va[tt][0], 0, 0, 0);
        va[tt][1] = __builtin_amdgcn_mfma_f32_16x16x32_bf16(xf, wv1, va[tt][1], 0, 0, 0);
      }
    }
    __builtin_amdgcn_s_setprio(0);
    #pragma unroll
    for (int dt = 0; dt < 2; ++dt) {
      unsigned bu[8];
      #pragma unroll
      for (int tt = 0; tt < 4; ++tt) {
        bu[tt * 2]     = pkbf(va[tt][dt][0], va[tt][dt][1]);
        bu[tt * 2 + 1] = pkbf(va[tt][dt][2], va[tt][dt][3]);
      }
      swp32(bu[0], bu[2]); swp32(bu[1], bu[3]); swp32(bu[4], bu[6]); swp32(bu[5], bu[7]);
      swp16(bu[0], bu[2]); swp16(bu[1], bu[3]); swp16(bu[4], bu[6]); swp16(bu[5], bu[7]);
      U8 z0, z1;
      z0.u[0] = bu[0]; z0.u[1] = bu[1]; z0.u[2] = bu[2]; z0.u[3] = bu[3];
      z1.u[0] = bu[4]; z1.u[1] = bu[5]; z1.u[2] = bu[6]; z1.u[3] = bu[7];
      vtf[dt][0] = z0.s;
      vtf[dt][1] = z1.s;
    }
  };

  auto QKg = [&](const unsigned short* xb, short8 (&qf)[4], short8 (&kf)[4]) {
    f32x4 Cq0 = *(const f32x4*)(bqkv + w * 32 + lhi * 4);
    f32x4 Cq1 = *(const f32x4*)(bqkv + w * 32 + 16 + lhi * 4);
    f32x4 Ck0 = *(const f32x4*)(bqkv + 256 + w * 32 + lhi * 4);
    f32x4 Ck1 = *(const f32x4*)(bqkv + 256 + w * 32 + 16 + lhi * 4);
    f32x4 qa[2][4], ka[2][4];
    #pragma unroll
    for (int tt = 0; tt < 4; ++tt) {
      qa[0][tt] = Cq0; qa[1][tt] = Cq1;
      ka[0][tt] = Ck0; ka[1][tt] = Ck1;
    }
    const unsigned short* wqp = Wqkv + (size_t)(w * 32 + l16) * 256 + lhi * 8;
    const unsigned short* wkp = wqp + 256 * 256;
    __builtin_amdgcn_s_setprio(1);
    #pragma unroll 2
    for (int kc = 0; kc < 8; ++kc) {
      short8 wq0 = *(const short8*)(wqp + kc * 32);
      short8 wq1 = *(const short8*)(wqp + 16 * 256 + kc * 32);
      short8 wk0 = *(const short8*)(wkp + kc * 32);
      short8 wk1 = *(const short8*)(wkp + 16 * 256 + kc * 32);
      #pragma unroll
      for (int tt = 0; tt < 4; ++tt) {
        short8 xf = *(const short8*)(&xb[(tt * 16 + l16) * 264 + kc * 32 + lhi * 8]);
        qa[0][tt] = __builtin_amdgcn_mfma_f32_16x16x32_bf16(wq0, xf, qa[0][tt], 0, 0, 0);
        qa[1][tt] = __builtin_amdgcn_mfma_f32_16x16x32_bf16(wq1, xf, qa[1][tt], 0, 0, 0);
        ka[0][tt] = __builtin_amdgcn_mfma_f32_16x16x32_bf16(wk0, xf, ka[0][tt], 0, 0, 0);
        ka[1][tt] = __builtin_amdgcn_mfma_f32_16x16x32_bf16(wk1, xf, ka[1][tt], 0, 0, 0);
      }
    }
    __builtin_amdgcn_s_setprio(0);
    #pragma unroll
    for (int tt = 0; tt < 4; ++tt) {
      unsigned a0 = pkbf(qa[0][tt][0], qa[0][tt][1]), a1 = pkbf(qa[0][tt][2], qa[0][tt][3]);
      unsigned a2 = pkbf(qa[1][tt][0], qa[1][tt][1]), a3 = pkbf(qa[1][tt][2], qa[1][tt][3]);
      swp32(a0, a2); swp32(a1, a3);
      swp16(a0, a2); swp16(a1, a3);
      U8 z; z.u[0] = a0; z.u[1] = a1; z.u[2] = a2; z.u[3] = a3;
      qf[tt] = z.s;
      unsigned c0 = pkbf(ka[0][tt][0], ka[0][tt][1]), c1 = pkbf(ka[0][tt][2], ka[0][tt][3]);
      unsigned c2 = pkbf(ka[1][tt][0], ka[1][tt][1]), c3 = pkbf(ka[1][tt][2], ka[1][tt][3]);
      swp32(c0, c2); swp32(c1, c3);
      swp16(c0, c2); swp16(c1, c3);
      U8 y; y.u[0] = c0; y.u[1] = c1; y.u[2] = c2; y.u[3] = c3;
      kf[tt] = y.s;
    }
  };

  // scores + softmax (no max-sub) + PV; writes normalized attn-out into xb
  auto SCg = [&](unsigned short* xb, short8 (&vtf)[2][2], short8 (&qf)[4], short8 (&kf)[4]) {
    #pragma unroll
    for (int nn = 0; nn < 4; ++nn) {
      f32x4 s[4];
      __builtin_amdgcn_s_setprio(1);
      #pragma unroll
      for (int m = 0; m < 4; ++m)
        s[m] = __builtin_amdgcn_mfma_f32_16x16x32_bf16(kf[m], qf[nn], (f32x4){0.f,0.f,0.f,0.f}, 0, 0, 0);
      __builtin_amdgcn_s_setprio(0);
      float sm[4];
      unsigned bu[8];
      #pragma unroll
      for (int m = 0; m < 4; ++m) {
        float e0 = exp2f(s[m][0] * K2);
        float e1 = exp2f(s[m][1] * K2);
        float e2 = exp2f(s[m][2] * K2);
        float e3 = exp2f(s[m][3] * K2);
        sm[m] = (e0 + e1) + (e2 + e3);
        bu[m * 2]     = pkbf(e0, e1);
        bu[m * 2 + 1] = pkbf(e2, e3);
      }
      float sum = (sm[0] + sm[1]) + (sm[2] + sm[3]);
      sum = redq_sum(sum);
      float iv = 1.0f / sum;
      swp32(bu[0], bu[2]); swp32(bu[1], bu[3]); swp32(bu[4], bu[6]); swp32(bu[5], bu[7]);
      swp16(bu[0], bu[2]); swp16(bu[1], bu[3]); swp16(bu[4], bu[6]); swp16(bu[5], bu[7]);
      U8 z0, z1;
      z0.u[0] = bu[0]; z0.u[1] = bu[1]; z0.u[2] = bu[2]; z0.u[3] = bu[3];
      z1.u[0] = bu[4]; z1.u[1] = bu[5]; z1.u[2] = bu[6]; z1.u[3] = bu[7];
      f32x4 ot0 = (f32x4){0.f,0.f,0.f,0.f};
      f32x4 ot1 = (f32x4){0.f,0.f,0.f,0.f};
      __builtin_amdgcn_s_setprio(1);
      ot0 = __builtin_amdgcn_mfma_f32_16x16x32_bf16(vtf[0][0], z0.s, ot0, 0, 0, 0);
      ot0 = __builtin_amdgcn_mfma_f32_16x16x32_bf16(vtf[0][1], z1.s, ot0, 0, 0, 0);
      ot1 = __builtin_amdgcn_mfma_f32_16x16x32_bf16(vtf[1][0], z0.s, ot1, 0, 0, 0);
      ot1 = __builtin_amdgcn_mfma_f32_16x16x32_bf16(vtf[1][1], z1.s, ot1, 0, 0, 0);
      __builtin_amdgcn_s_setprio(0);
      uint2v o0, o1;
      o0.x = pkbf(ot0[0] * iv, ot0[1] * iv);
      o0.y = pkbf(ot0[2] * iv, ot0[3] * iv);
      o1.x = pkbf(ot1[0] * iv, ot1[1] * iv);
      o1.y = pkbf(ot1[2] * iv, ot1[3] * iv);
      *(uint2v*)(&xb[(nn * 16 + l16) * 264 + w * 32 + lhi * 4]) = o0;
      *(uint2v*)(&xb[(nn * 16 + l16) * 264 + w * 32 + 16 + lhi * 4]) = o1;
    }
  };

  auto OPg = [&](const unsigned short* xb, int b, int wi, int wj) {
    float ob0 = boG[w * 32 + l16];
    float ob1 = boG[w * 32 + 16 + l16];
    f32x4 ya[4][2];
    #pragma unroll
    for (int mt = 0; mt < 4; ++mt) {
      ya[mt][0] = (f32x4){ob0, ob0, ob0, ob0};
      ya[mt][1] = (f32x4){ob1, ob1, ob1, ob1};
    }
    const unsigned short* wop = Wout + (size_t)(w * 32 + l16) * 256 + lhi * 8;
    __builtin_amdgcn_s_setprio(1);
    #pragma unroll 4
    for (int kc = 0; kc < 8; ++kc) {
      short8 wf0 = *(const short8*)(wop + kc * 32);
      short8 wf1 = *(const short8*)(wop + 16 * 256 + kc * 32);
      #pragma unroll
      for (int mt = 0; mt < 4; ++mt) {
        short8 af = *(const short8*)(&xb[(mt * 16 + l16) * 264 + kc * 32 + lhi * 8]);
        ya[mt][0] = __builtin_amdgcn_mfma_f32_16x16x32_bf16(af, wf0, ya[mt][0], 0, 0, 0);
        ya[mt][1] = __builtin_amdgcn_mfma_f32_16x16x32_bf16(af, wf1, ya[mt][1], 0, 0, 0);
      }
    }
    __builtin_amdgcn_s_setprio(0);
    #pragma unroll
    for (int mt = 0; mt < 4; ++mt)
      #pragma unroll
      for (int r = 0; r < 4; ++r) {
        int row = mt * 16 + lhi * 4 + r;
        int a = row >> 3, cg = row & 7;
        float* pout = out + ((size_t)((b * 128 + a * 16 + wi) * 128 + cg * 16 + wj)) * 256 + w * 32;
        pout[l16]      = ya[mt][0][r];
        pout[l16 + 16] = ya[mt][1][r];
      }
  };

  // ---------- window A compute ----------
  short8 vtfA[2][2], qfA[4], kfA[4];
  Vg(&ldsX[0][0], vtfA);
  QKg(&ldsX[0][0], qfA, kfA);
  __syncthreads();               // bar2: all ldsX[0] reads done -> SC may overwrite

  SCg(&ldsX[0][0], vtfA, qfA, kfA);   // writes attn-out A

  // ---------- window B compute (overlaps SC(A) in the issue stream) ----------
  short8 vtfB[2][2], qfB[4], kfB[4];
  Vg(&ldsX[1][0], vtfB);
  QKg(&ldsX[1][0], qfB, kfB);
  __syncthreads();               // bar3: ldsX[1] reads done + SC(A) writes visible

  SCg(&ldsX[1][0], vtfB, qfB, kfB);   // writes attn-out B
  OPg(&ldsX[0][0], bA, wiA, wjA);     // out_proj A (overlaps SC(B))
  __syncthreads();               // bar4: SC(B) writes visible
  OPg(&ldsX[1][0], bB, wiB, wjB);     // out_proj B
}

extern "C" void kernel_launch(void* const* d_in, const int* in_sizes, int n_in,
                              void* d_out, int out_size, void* d_ws, size_t ws_size,
                              hipStream_t stream) {
  const float* x    = (const float*)d_in[0];
  const float* ln_w = (const float*)d_in[1];
  const float* ln_b = (const float*)d_in[2];
  const float* ipw  = (const float*)d_in[3];
  const float* ipb  = (const float*)d_in[4];
  const float* opw  = (const float*)d_in[5];
  const float* opb  = (const float*)d_in[6];
  const float* gm   = (const float*)d_in[7];

  unsigned short* wbf = (unsigned short*)d_ws;          // [0,196608) Wqkv bf16 ; [196608,262144) Wout∘γ bf16
  float* boG = (float*)(wbf + 262144);                  // [256]

  prep<<<1024, 64, 0, stream>>>(ipw, opw, gm, opb, wbf, boG);
  grid_attn<<<2048, 512, 0, stream>>>(x, ln_w, ln_b, wbf, ipb,
                                      wbf + 196608, boG, (float*)d_out);
}